// Round 18
// baseline (236.103 us; speedup 1.0000x reference)
//
#include <hip/hip_runtime.h>
#include <hip/hip_cooperative_groups.h>
#include <math.h>

namespace cg = cooperative_groups;

// Problem constants (match reference)
#define PH 256
#define PW 512
#define NRAYS (PH * PW)     // 131072
#define NS 300
#define NB64 (NRAYS / 64)   // 2048 one-wave blocks
#define PI_F 3.14159265358979323846f

// Early-termination threshold. Validated model (r12/r13): T ~ e^{-0.107 n},
// truncation error scales linearly with T_BREAK (1e-4 -> absmax 0.0039,
// 1e-3 -> 0.0078). 2e-3 stops at n~58, expected absmax ~0.012 < 2e-2.
#define T_BREAK 2e-3f

// Render reads the original voxel (64 slices of 256x256) directly.
// Ground slab (cell z0==0): node 0 = constant 1000, node 1 = voxel slice 0
// -> 4 cndmasks at consume time. Tight ray-box clip keeps x0,y0 in [0,254],
// z0 in [0,63] for every marched (and prefetch-clamped) sample.

__device__ __forceinline__ float lerpf(float a, float b, float f) {
    return fmaf(f, b - a, a);
}

// One in-flight sample: 8 corners + fractions + ground flag. Two named
// 4-sample register sets (A/B) ping-pong through a manually 2-unrolled
// loop so all indexing is compile-time (no scratch). (r15-proven: 2-deep
// covers the latency; 3-deep null; float4 pairing regresses.)
struct Smp {
    float c0, c1, c2, c3, c4, c5, c6, c7;
    float fx, fy, fz;
    bool g;
};

#define LOADS(S, fsbase)                                                   \
    _Pragma("unroll")                                                      \
    for (int j = 0; j < 4; ++j) {                                          \
        const float fs = fminf((fsbase) + (float)(j + 1), fnrun);          \
        const float xf = fmaf(fs, sxd, 127.5f);                            \
        const float yf = fmaf(fs, syd, 127.5f);                            \
        const float zf = fmaf(fs, szd, 1.53125f);                          \
        const float xw = floorf(xf), yw = floorf(yf), zw = floorf(zf);     \
        S[j].fx = xf - xw; S[j].fy = yf - yw; S[j].fz = zf - zw;           \
        const int x0 = (int)xw, y0 = (int)yw, z0 = (int)zw;                \
        const int zlo = (z0 > 0) ? (z0 - 1) : 0;                           \
        S[j].g = (z0 == 0);                                                \
        const int xy = (y0 << 8) + x0;                                     \
        const float* pLo = vox + ((zlo << 16) + xy);                       \
        const float* pHi = vox + ((z0 << 16) + xy);                        \
        S[j].c0 = pLo[0];   S[j].c1 = pLo[1];                              \
        S[j].c2 = pLo[256]; S[j].c3 = pLo[257];                            \
        S[j].c4 = pHi[0];   S[j].c5 = pHi[1];                              \
        S[j].c6 = pHi[256]; S[j].c7 = pHi[257];                            \
    }

#define CONS(S)                                                            \
    _Pragma("unroll")                                                      \
    for (int j = 0; j < 4; ++j) {                                          \
        const float d000 = S[j].g ? 1000.0f : S[j].c0;                     \
        const float d001 = S[j].g ? 1000.0f : S[j].c1;                     \
        const float d010 = S[j].g ? 1000.0f : S[j].c2;                     \
        const float d011 = S[j].g ? 1000.0f : S[j].c3;                     \
        const float l00 = lerpf(d000, d001, S[j].fx);                      \
        const float l01 = lerpf(d010, d011, S[j].fx);                      \
        const float l10 = lerpf(S[j].c4, S[j].c5, S[j].fx);                \
        const float l11 = lerpf(S[j].c6, S[j].c7, S[j].fx);                \
        const float sg = lerpf(lerpf(l00, l01, S[j].fy),                   \
                               lerpf(l10, l11, S[j].fy), S[j].fz);         \
        const float e = __expf(-sg * intv);                                \
        const float prob = fmaf(-T, e, T);                                 \
        dval += intv;                                                      \
        depth = fmaf(prob, dval, depth);                                   \
        opac += prob;                                                      \
        T *= e;                                                            \
    }

__device__ __forceinline__ float sample_sigma(const float* __restrict__ vox,
                                              float fs, float sxd, float syd, float szd) {
    const float xf = fmaf(fs, sxd, 127.5f);
    const float yf = fmaf(fs, syd, 127.5f);
    const float zf = fmaf(fs, szd, 1.53125f);
    const float xw = floorf(xf), yw = floorf(yf), zw = floorf(zf);
    const float fx = xf - xw, fy = yf - yw, fz = zf - zw;
    const int x0 = (int)xw, y0 = (int)yw, z0 = (int)zw;
    const int zlo = (z0 > 0) ? (z0 - 1) : 0;
    const bool gnd = (z0 == 0);
    const int xy = (y0 << 8) + x0;
    const float* pLo = vox + ((zlo << 16) + xy);
    const float* pHi = vox + ((z0 << 16) + xy);
    const float c000 = gnd ? 1000.0f : pLo[0];
    const float c001 = gnd ? 1000.0f : pLo[1];
    const float c010 = gnd ? 1000.0f : pLo[256];
    const float c011 = gnd ? 1000.0f : pLo[257];
    const float c100 = pHi[0];
    const float c101 = pHi[1];
    const float c110 = pHi[256];
    const float c111 = pHi[257];
    const float l00 = lerpf(c000, c001, fx);
    const float l01 = lerpf(c010, c011, fx);
    const float l10 = lerpf(c100, c101, fx);
    const float l11 = lerpf(c110, c111, fx);
    return lerpf(lerpf(l00, l01, fy), lerpf(l10, l11, fy), fz);
}

// Single cooperative kernel: render -> grid.sync -> reduce+normalize.
// __launch_bounds__(64,2): min 2 waves/SIMD caps VGPR <= 256, guaranteeing
// all 2048 one-wave blocks are co-resident (8 blocks/CU) for the grid sync.
__global__ __launch_bounds__(64, 2)
void fused_kernel(const float* __restrict__ vox,
                  float* __restrict__ out,
                  float* __restrict__ bmin, float* __restrict__ bmax) {
    const int lane = threadIdx.x;
    const int r = blockIdx.x * 64 + lane;
    const int h = r >> 9;
    const int w = r & (PW - 1);

    const float lat = (0.5f - (float)h * (1.0f / 255.0f)) * PI_F;
    const float lon = (-0.5f - 2.0f * (float)w * (1.0f / 511.0f)) * PI_F;
    float cl, sl, clon, slon;
    __sincosf(lat, &sl, &cl);
    __sincosf(lon, &slon, &clon);
    const float sxd = cl * clon * (128.0f / NS);
    const float syd = -cl * slon * (128.0f / NS);
    const float szd = sl * (65.0f / NS);
    const float intv = 64.0f / (float)NS;

    // Tight ray-box clip: xf,yf in [m,255-m], zf in [m,64-m] -> x0,y0 in
    // [0,254], z0 in [0,63] for all marched samples. Clipped region is
    // provably dead (T=0 below ground / sigma=0 or T-break fires first).
    const float m = 1e-3f;
    float nx = 1e9f, ny = 1e9f, nz = 1e9f;
    if (sxd >  1e-8f) nx = (255.0f - m - 127.5f) / sxd;
    if (sxd < -1e-8f) nx = (127.5f - m) / (-sxd);
    if (syd >  1e-8f) ny = (255.0f - m - 127.5f) / syd;
    if (syd < -1e-8f) ny = (127.5f - m) / (-syd);
    if (szd >  1e-8f) nz = (64.0f - m - 1.53125f) / szd;
    if (szd < -1e-8f) nz = (1.53125f - m) / (-szd);
    const float nmin = fminf(fminf(nx, ny), nz);
    int nrun = NS;
    if (nmin < (float)NS) nrun = (int)nmin;
    if (nrun < 0) nrun = 0;
    const float fnrun = (float)nrun;

    float T = 1.0f, depth = 0.0f, opac = 0.0f, dval = 0.0f;

    int i = 0;
    // 2-deep software pipeline (r15-proven).
    if (nrun >= 4) {
        Smp A[4], B[4];
        LOADS(A, 0.0f)
        for (;;) {
            LOADS(B, (float)(i + 4))
            CONS(A)
            i += 4;
            if ((T < T_BREAK) | (i + 4 > nrun)) break;
            LOADS(A, (float)(i + 4))
            CONS(B)
            i += 4;
            if ((T < T_BREAK) | (i + 4 > nrun)) break;
        }
    }
    if (T >= T_BREAK) {
        for (; i < nrun; ++i) {
            const float sg = sample_sigma(vox, (float)(i + 1), sxd, syd, szd);
            const float e = __expf(-sg * intv);
            const float prob = fmaf(-T, e, T);
            dval += intv;
            depth = fmaf(prob, dval, depth);
            opac += prob;
            T *= e;
            if (T < T_BREAK) break;
        }
    }

    // opacity is final now; depth stays in a register across the sync
    out[NRAYS + r] = opac;

    float mn = depth, mx = depth;
    #pragma unroll
    for (int off = 32; off > 0; off >>= 1) {
        mn = fminf(mn, __shfl_xor(mn, off));
        mx = fmaxf(mx, __shfl_xor(mx, off));
    }
    if (lane == 0) {
        bmin[blockIdx.x] = mn;
        bmax[blockIdx.x] = mx;
    }

    cg::this_grid().sync();

    // Every block redundantly reduces the 2048-entry bmin/bmax (L2-hot),
    // then normalizes its own 64 depths straight from registers.
    float gmn = 1e30f, gmx = -1e30f;
    #pragma unroll
    for (int k = 0; k < NB64 / 64; ++k) {
        gmn = fminf(gmn, bmin[k * 64 + lane]);
        gmx = fmaxf(gmx, bmax[k * 64 + lane]);
    }
    #pragma unroll
    for (int off = 32; off > 0; off >>= 1) {
        gmn = fminf(gmn, __shfl_xor(gmn, off));
        gmx = fmaxf(gmx, __shfl_xor(gmx, off));
    }
    out[r] = (depth - gmn) / (gmx - gmn);
}

extern "C" void kernel_launch(void* const* d_in, const int* in_sizes, int n_in,
                              void* d_out, int out_size, void* d_ws, size_t ws_size,
                              hipStream_t stream) {
    const float* vox = (const float*)d_in[0];
    float* out = (float*)d_out;
    char* ws = (char*)d_ws;
    float* bmin = (float*)ws;               // 2048 floats
    float* bmax = (float*)(ws + 8192);      // 2048 floats

    void* args[] = {(void*)&vox, (void*)&out, (void*)&bmin, (void*)&bmax};
    hipLaunchCooperativeKernel((const void*)fused_kernel,
                               dim3(NB64), dim3(64), args, 0, stream);
}

// Round 19
// 23.067 us; speedup vs baseline: 10.2356x; 10.2356x over previous
//
#include <hip/hip_runtime.h>
#include <math.h>

// Problem constants (match reference)
#define PH 256
#define PW 512
#define NRAYS (PH * PW)     // 131072
#define NS 300
#define NB64 (NRAYS / 64)   // 2048 one-wave blocks
#define PI_F 3.14159265358979323846f

// Early-termination threshold. Validated model (r12/r13/r18): T ~ e^{-0.107 n},
// truncation error scales linearly with T_BREAK (1e-4 -> absmax 0.0039,
// 1e-3 -> 0.0078, 2e-3 -> 0.0117 measured r18). Threshold is 2e-2.
#define T_BREAK 2e-3f

// Render reads the original voxel (64 slices of 256x256) directly.
// Ground slab (cell z0==0): node 0 = constant 1000, node 1 = voxel slice 0
// -> 4 cndmasks at consume time. Tight ray-box clip keeps x0,y0 in [0,254],
// z0 in [0,63] for every marched (and prefetch-clamped) sample.

__device__ __forceinline__ float lerpf(float a, float b, float f) {
    return fmaf(f, b - a, a);
}

// One in-flight sample: 8 corners + fractions + ground flag. Two named
// 4-sample register sets (A/B) ping-pong through a manually 2-unrolled
// loop so all indexing is compile-time (no scratch). (r15-proven: 2-deep
// covers the latency; 3-deep null (r16); float4 pairing regresses (r17);
// coop grid-sync fusion catastrophic (r18).)
struct Smp {
    float c0, c1, c2, c3, c4, c5, c6, c7;
    float fx, fy, fz;
    bool g;
};

#define LOADS(S, fsbase)                                                   \
    _Pragma("unroll")                                                      \
    for (int j = 0; j < 4; ++j) {                                          \
        const float fs = fminf((fsbase) + (float)(j + 1), fnrun);          \
        const float xf = fmaf(fs, sxd, 127.5f);                            \
        const float yf = fmaf(fs, syd, 127.5f);                            \
        const float zf = fmaf(fs, szd, 1.53125f);                          \
        const float xw = floorf(xf), yw = floorf(yf), zw = floorf(zf);     \
        S[j].fx = xf - xw; S[j].fy = yf - yw; S[j].fz = zf - zw;           \
        const int x0 = (int)xw, y0 = (int)yw, z0 = (int)zw;                \
        const int zlo = (z0 > 0) ? (z0 - 1) : 0;                           \
        S[j].g = (z0 == 0);                                                \
        const int xy = (y0 << 8) + x0;                                     \
        const float* pLo = vox + ((zlo << 16) + xy);                       \
        const float* pHi = vox + ((z0 << 16) + xy);                        \
        S[j].c0 = pLo[0];   S[j].c1 = pLo[1];                              \
        S[j].c2 = pLo[256]; S[j].c3 = pLo[257];                            \
        S[j].c4 = pHi[0];   S[j].c5 = pHi[1];                              \
        S[j].c6 = pHi[256]; S[j].c7 = pHi[257];                            \
    }

#define CONS(S)                                                            \
    _Pragma("unroll")                                                      \
    for (int j = 0; j < 4; ++j) {                                          \
        const float d000 = S[j].g ? 1000.0f : S[j].c0;                     \
        const float d001 = S[j].g ? 1000.0f : S[j].c1;                     \
        const float d010 = S[j].g ? 1000.0f : S[j].c2;                     \
        const float d011 = S[j].g ? 1000.0f : S[j].c3;                     \
        const float l00 = lerpf(d000, d001, S[j].fx);                      \
        const float l01 = lerpf(d010, d011, S[j].fx);                      \
        const float l10 = lerpf(S[j].c4, S[j].c5, S[j].fx);                \
        const float l11 = lerpf(S[j].c6, S[j].c7, S[j].fx);                \
        const float sg = lerpf(lerpf(l00, l01, S[j].fy),                   \
                               lerpf(l10, l11, S[j].fy), S[j].fz);         \
        const float e = __expf(-sg * intv);                                \
        const float prob = fmaf(-T, e, T);                                 \
        dval += intv;                                                      \
        depth = fmaf(prob, dval, depth);                                   \
        opac += prob;                                                      \
        T *= e;                                                            \
    }

__device__ __forceinline__ float sample_sigma(const float* __restrict__ vox,
                                              float fs, float sxd, float syd, float szd) {
    const float xf = fmaf(fs, sxd, 127.5f);
    const float yf = fmaf(fs, syd, 127.5f);
    const float zf = fmaf(fs, szd, 1.53125f);
    const float xw = floorf(xf), yw = floorf(yf), zw = floorf(zf);
    const float fx = xf - xw, fy = yf - yw, fz = zf - zw;
    const int x0 = (int)xw, y0 = (int)yw, z0 = (int)zw;
    const int zlo = (z0 > 0) ? (z0 - 1) : 0;
    const bool gnd = (z0 == 0);
    const int xy = (y0 << 8) + x0;
    const float* pLo = vox + ((zlo << 16) + xy);
    const float* pHi = vox + ((z0 << 16) + xy);
    const float c000 = gnd ? 1000.0f : pLo[0];
    const float c001 = gnd ? 1000.0f : pLo[1];
    const float c010 = gnd ? 1000.0f : pLo[256];
    const float c011 = gnd ? 1000.0f : pLo[257];
    const float c100 = pHi[0];
    const float c101 = pHi[1];
    const float c110 = pHi[256];
    const float c111 = pHi[257];
    const float l00 = lerpf(c000, c001, fx);
    const float l01 = lerpf(c010, c011, fx);
    const float l10 = lerpf(c100, c101, fx);
    const float l11 = lerpf(c110, c111, fx);
    return lerpf(lerpf(l00, l01, fy), lerpf(l10, l11, fy), fz);
}

__global__ __launch_bounds__(64)
void render_kernel(const float* __restrict__ vox,
                   float* __restrict__ out,
                   float* __restrict__ bmin, float* __restrict__ bmax) {
    const int lane = threadIdx.x;
    const int r = blockIdx.x * 64 + lane;
    const int h = r >> 9;
    const int w = r & (PW - 1);

    const float lat = (0.5f - (float)h * (1.0f / 255.0f)) * PI_F;
    const float lon = (-0.5f - 2.0f * (float)w * (1.0f / 511.0f)) * PI_F;
    float cl, sl, clon, slon;
    __sincosf(lat, &sl, &cl);
    __sincosf(lon, &slon, &clon);
    const float sxd = cl * clon * (128.0f / NS);
    const float syd = -cl * slon * (128.0f / NS);
    const float szd = sl * (65.0f / NS);
    const float intv = 64.0f / (float)NS;

    // Tight ray-box clip: xf,yf in [m,255-m], zf in [m,64-m] -> x0,y0 in
    // [0,254], z0 in [0,63] for all marched samples. Clipped region is
    // provably dead (T=0 below ground / sigma=0 or T-break fires first).
    const float m = 1e-3f;
    float nx = 1e9f, ny = 1e9f, nz = 1e9f;
    if (sxd >  1e-8f) nx = (255.0f - m - 127.5f) / sxd;
    if (sxd < -1e-8f) nx = (127.5f - m) / (-sxd);
    if (syd >  1e-8f) ny = (255.0f - m - 127.5f) / syd;
    if (syd < -1e-8f) ny = (127.5f - m) / (-syd);
    if (szd >  1e-8f) nz = (64.0f - m - 1.53125f) / szd;
    if (szd < -1e-8f) nz = (1.53125f - m) / (-szd);
    const float nmin = fminf(fminf(nx, ny), nz);
    int nrun = NS;
    if (nmin < (float)NS) nrun = (int)nmin;
    if (nrun < 0) nrun = 0;
    const float fnrun = (float)nrun;

    float T = 1.0f, depth = 0.0f, opac = 0.0f, dval = 0.0f;

    int i = 0;
    // 2-deep software pipeline: batch i+4's 32 loads are issued before
    // batch i is consumed, so consume math hides load latency (r15-proven).
    if (nrun >= 4) {
        Smp A[4], B[4];
        LOADS(A, 0.0f)
        for (;;) {
            LOADS(B, (float)(i + 4))
            CONS(A)
            i += 4;
            if ((T < T_BREAK) | (i + 4 > nrun)) break;
            LOADS(A, (float)(i + 4))
            CONS(B)
            i += 4;
            if ((T < T_BREAK) | (i + 4 > nrun)) break;
        }
    }
    // scalar tail
    if (T >= T_BREAK) {
        for (; i < nrun; ++i) {
            const float sg = sample_sigma(vox, (float)(i + 1), sxd, syd, szd);
            const float e = __expf(-sg * intv);
            const float prob = fmaf(-T, e, T);
            dval += intv;
            depth = fmaf(prob, dval, depth);
            opac += prob;
            T *= e;
            if (T < T_BREAK) break;
        }
    }

    out[r] = depth;
    out[NRAYS + r] = opac;

    // wave min/max of depth
    float mn = depth, mx = depth;
    #pragma unroll
    for (int off = 32; off > 0; off >>= 1) {
        mn = fminf(mn, __shfl_xor(mn, off));
        mx = fmaxf(mx, __shfl_xor(mx, off));
    }
    if (lane == 0) {
        bmin[blockIdx.x] = mn;
        bmax[blockIdx.x] = mx;
    }
}

// Fused: every block redundantly reduces the 2048-entry bmin/bmax arrays
// (16 KB, L2-hot, ~free) then normalizes its 256-ray slice of depth.
__global__ __launch_bounds__(256)
void normalize_fused_kernel(float* __restrict__ out,
                            const float* __restrict__ blockMin,
                            const float* __restrict__ blockMax) {
    const int t = threadIdx.x;
    float mn = 1e30f, mx = -1e30f;
    #pragma unroll
    for (int k = 0; k < NB64 / 256; ++k) {
        mn = fminf(mn, blockMin[k * 256 + t]);
        mx = fmaxf(mx, blockMax[k * 256 + t]);
    }
    #pragma unroll
    for (int off = 32; off > 0; off >>= 1) {
        mn = fminf(mn, __shfl_xor(mn, off));
        mx = fmaxf(mx, __shfl_xor(mx, off));
    }
    __shared__ float smn[4], smx[4];
    if ((t & 63) == 0) {
        smn[t >> 6] = mn;
        smx[t >> 6] = mx;
    }
    __syncthreads();
    mn = fminf(fminf(smn[0], smn[1]), fminf(smn[2], smn[3]));
    mx = fmaxf(fmaxf(smx[0], smx[1]), fmaxf(smx[2], smx[3]));

    const int r = blockIdx.x * 256 + t;
    out[r] = (out[r] - mn) / (mx - mn);
}

extern "C" void kernel_launch(void* const* d_in, const int* in_sizes, int n_in,
                              void* d_out, int out_size, void* d_ws, size_t ws_size,
                              hipStream_t stream) {
    const float* vox = (const float*)d_in[0];
    float* out = (float*)d_out;
    char* ws = (char*)d_ws;
    float* bmin = (float*)ws;               // 2048 floats
    float* bmax = (float*)(ws + 8192);      // 2048 floats

    render_kernel<<<NB64, 64, 0, stream>>>(vox, out, bmin, bmax);
    normalize_fused_kernel<<<NRAYS / 256, 256, 0, stream>>>(out, bmin, bmax);
}

// Round 20
// 22.948 us; speedup vs baseline: 10.2886x; 1.0052x over previous
//
#include <hip/hip_runtime.h>
#include <math.h>

// Problem constants (match reference)
#define PH 256
#define PW 512
#define NRAYS (PH * PW)     // 131072
#define NS 300
#define NB64 (NRAYS / 64)   // 2048 one-wave blocks
#define PI_F 3.14159265358979323846f

// Early-termination threshold. Validated model (r12/r13/r18): T ~ e^{-0.107 n},
// truncation error scales linearly with T_BREAK (1e-4 -> absmax 0.0039,
// 1e-3 -> 0.0078, 2e-3 -> 0.0117 measured r18). Threshold is 2e-2.
#define T_BREAK 2e-3f

// Render reads the original voxel (64 slices of 256x256) directly.
// Ground slab (cell z0==0): node 0 = constant 1000, node 1 = voxel slice 0
// -> 4 cndmasks at consume time. Tight ray-box clip keeps x0,y0 in [0,254],
// z0 in [0,63] for every marched (and prefetch-clamped) sample.

__device__ __forceinline__ float lerpf(float a, float b, float f) {
    return fmaf(f, b - a, a);
}

// One in-flight sample: 8 corners + fractions + ground flag. Two named
// 4-sample register sets (A/B) ping-pong through a manually 2-unrolled
// loop so all indexing is compile-time (no scratch). (r15-proven: 2-deep
// covers the latency; 3-deep null (r16); float4 pairing regresses (r17);
// coop grid-sync fusion catastrophic (r18).)
struct Smp {
    float c0, c1, c2, c3, c4, c5, c6, c7;
    float fx, fy, fz;
    bool g;
};

#define LOADS(S, fsbase)                                                   \
    _Pragma("unroll")                                                      \
    for (int j = 0; j < 4; ++j) {                                          \
        const float fs = fminf((fsbase) + (float)(j + 1), fnrun);          \
        const float xf = fmaf(fs, sxd, 127.5f);                            \
        const float yf = fmaf(fs, syd, 127.5f);                            \
        const float zf = fmaf(fs, szd, 1.53125f);                          \
        const float xw = floorf(xf), yw = floorf(yf), zw = floorf(zf);     \
        S[j].fx = xf - xw; S[j].fy = yf - yw; S[j].fz = zf - zw;           \
        const int x0 = (int)xw, y0 = (int)yw, z0 = (int)zw;                \
        const int zlo = (z0 > 0) ? (z0 - 1) : 0;                           \
        S[j].g = (z0 == 0);                                                \
        const int xy = (y0 << 8) + x0;                                     \
        const float* pLo = vox + ((zlo << 16) + xy);                       \
        const float* pHi = vox + ((z0 << 16) + xy);                        \
        S[j].c0 = pLo[0];   S[j].c1 = pLo[1];                              \
        S[j].c2 = pLo[256]; S[j].c3 = pLo[257];                            \
        S[j].c4 = pHi[0];   S[j].c5 = pHi[1];                              \
        S[j].c6 = pHi[256]; S[j].c7 = pHi[257];                            \
    }

#define CONS(S)                                                            \
    _Pragma("unroll")                                                      \
    for (int j = 0; j < 4; ++j) {                                          \
        const float d000 = S[j].g ? 1000.0f : S[j].c0;                     \
        const float d001 = S[j].g ? 1000.0f : S[j].c1;                     \
        const float d010 = S[j].g ? 1000.0f : S[j].c2;                     \
        const float d011 = S[j].g ? 1000.0f : S[j].c3;                     \
        const float l00 = lerpf(d000, d001, S[j].fx);                      \
        const float l01 = lerpf(d010, d011, S[j].fx);                      \
        const float l10 = lerpf(S[j].c4, S[j].c5, S[j].fx);                \
        const float l11 = lerpf(S[j].c6, S[j].c7, S[j].fx);                \
        const float sg = lerpf(lerpf(l00, l01, S[j].fy),                   \
                               lerpf(l10, l11, S[j].fy), S[j].fz);         \
        const float e = __expf(-sg * intv);                                \
        const float prob = fmaf(-T, e, T);                                 \
        dval += intv;                                                      \
        depth = fmaf(prob, dval, depth);                                   \
        opac += prob;                                                      \
        T *= e;                                                            \
    }

__device__ __forceinline__ float sample_sigma(const float* __restrict__ vox,
                                              float fs, float sxd, float syd, float szd) {
    const float xf = fmaf(fs, sxd, 127.5f);
    const float yf = fmaf(fs, syd, 127.5f);
    const float zf = fmaf(fs, szd, 1.53125f);
    const float xw = floorf(xf), yw = floorf(yf), zw = floorf(zf);
    const float fx = xf - xw, fy = yf - yw, fz = zf - zw;
    const int x0 = (int)xw, y0 = (int)yw, z0 = (int)zw;
    const int zlo = (z0 > 0) ? (z0 - 1) : 0;
    const bool gnd = (z0 == 0);
    const int xy = (y0 << 8) + x0;
    const float* pLo = vox + ((zlo << 16) + xy);
    const float* pHi = vox + ((z0 << 16) + xy);
    const float c000 = gnd ? 1000.0f : pLo[0];
    const float c001 = gnd ? 1000.0f : pLo[1];
    const float c010 = gnd ? 1000.0f : pLo[256];
    const float c011 = gnd ? 1000.0f : pLo[257];
    const float c100 = pHi[0];
    const float c101 = pHi[1];
    const float c110 = pHi[256];
    const float c111 = pHi[257];
    const float l00 = lerpf(c000, c001, fx);
    const float l01 = lerpf(c010, c011, fx);
    const float l10 = lerpf(c100, c101, fx);
    const float l11 = lerpf(c110, c111, fx);
    return lerpf(lerpf(l00, l01, fy), lerpf(l10, l11, fy), fz);
}

__global__ __launch_bounds__(64)
void render_kernel(const float* __restrict__ vox,
                   float* __restrict__ out,
                   float* __restrict__ bmin, float* __restrict__ bmax) {
    const int lane = threadIdx.x;
    const int r = blockIdx.x * 64 + lane;
    const int h = r >> 9;
    const int w = r & (PW - 1);

    const float lat = (0.5f - (float)h * (1.0f / 255.0f)) * PI_F;
    const float lon = (-0.5f - 2.0f * (float)w * (1.0f / 511.0f)) * PI_F;
    float cl, sl, clon, slon;
    __sincosf(lat, &sl, &cl);
    __sincosf(lon, &slon, &clon);
    const float sxd = cl * clon * (128.0f / NS);
    const float syd = -cl * slon * (128.0f / NS);
    const float szd = sl * (65.0f / NS);
    const float intv = 64.0f / (float)NS;

    // Tight ray-box clip: xf,yf in [m,255-m], zf in [m,64-m] -> x0,y0 in
    // [0,254], z0 in [0,63] for all marched samples. Clipped region is
    // provably dead (T=0 below ground / sigma=0 or T-break fires first).
    const float m = 1e-3f;
    float nx = 1e9f, ny = 1e9f, nz = 1e9f;
    if (sxd >  1e-8f) nx = (255.0f - m - 127.5f) / sxd;
    if (sxd < -1e-8f) nx = (127.5f - m) / (-sxd);
    if (syd >  1e-8f) ny = (255.0f - m - 127.5f) / syd;
    if (syd < -1e-8f) ny = (127.5f - m) / (-syd);
    if (szd >  1e-8f) nz = (64.0f - m - 1.53125f) / szd;
    if (szd < -1e-8f) nz = (1.53125f - m) / (-szd);
    const float nmin = fminf(fminf(nx, ny), nz);
    int nrun = NS;
    if (nmin < (float)NS) nrun = (int)nmin;
    if (nrun < 0) nrun = 0;
    const float fnrun = (float)nrun;

    float T = 1.0f, depth = 0.0f, opac = 0.0f, dval = 0.0f;

    int i = 0;
    // 2-deep software pipeline: batch i+4's 32 loads are issued before
    // batch i is consumed, so consume math hides load latency (r15-proven).
    if (nrun >= 4) {
        Smp A[4], B[4];
        LOADS(A, 0.0f)
        for (;;) {
            LOADS(B, (float)(i + 4))
            CONS(A)
            i += 4;
            if ((T < T_BREAK) | (i + 4 > nrun)) break;
            LOADS(A, (float)(i + 4))
            CONS(B)
            i += 4;
            if ((T < T_BREAK) | (i + 4 > nrun)) break;
        }
    }
    // scalar tail
    if (T >= T_BREAK) {
        for (; i < nrun; ++i) {
            const float sg = sample_sigma(vox, (float)(i + 1), sxd, syd, szd);
            const float e = __expf(-sg * intv);
            const float prob = fmaf(-T, e, T);
            dval += intv;
            depth = fmaf(prob, dval, depth);
            opac += prob;
            T *= e;
            if (T < T_BREAK) break;
        }
    }

    out[r] = depth;
    out[NRAYS + r] = opac;

    // wave min/max of depth
    float mn = depth, mx = depth;
    #pragma unroll
    for (int off = 32; off > 0; off >>= 1) {
        mn = fminf(mn, __shfl_xor(mn, off));
        mx = fmaxf(mx, __shfl_xor(mx, off));
    }
    if (lane == 0) {
        bmin[blockIdx.x] = mn;
        bmax[blockIdx.x] = mx;
    }
}

// Fused: every block redundantly reduces the 2048-entry bmin/bmax arrays
// (16 KB, L2-hot, ~free) then normalizes its 256-ray slice of depth.
__global__ __launch_bounds__(256)
void normalize_fused_kernel(float* __restrict__ out,
                            const float* __restrict__ blockMin,
                            const float* __restrict__ blockMax) {
    const int t = threadIdx.x;
    float mn = 1e30f, mx = -1e30f;
    #pragma unroll
    for (int k = 0; k < NB64 / 256; ++k) {
        mn = fminf(mn, blockMin[k * 256 + t]);
        mx = fmaxf(mx, blockMax[k * 256 + t]);
    }
    #pragma unroll
    for (int off = 32; off > 0; off >>= 1) {
        mn = fminf(mn, __shfl_xor(mn, off));
        mx = fmaxf(mx, __shfl_xor(mx, off));
    }
    __shared__ float smn[4], smx[4];
    if ((t & 63) == 0) {
        smn[t >> 6] = mn;
        smx[t >> 6] = mx;
    }
    __syncthreads();
    mn = fminf(fminf(smn[0], smn[1]), fminf(smn[2], smn[3]));
    mx = fmaxf(fmaxf(smx[0], smx[1]), fmaxf(smx[2], smx[3]));

    const int r = blockIdx.x * 256 + t;
    out[r] = (out[r] - mn) / (mx - mn);
}

extern "C" void kernel_launch(void* const* d_in, const int* in_sizes, int n_in,
                              void* d_out, int out_size, void* d_ws, size_t ws_size,
                              hipStream_t stream) {
    const float* vox = (const float*)d_in[0];
    float* out = (float*)d_out;
    char* ws = (char*)d_ws;
    float* bmin = (float*)ws;               // 2048 floats
    float* bmax = (float*)(ws + 8192);      // 2048 floats

    render_kernel<<<NB64, 64, 0, stream>>>(vox, out, bmin, bmax);
    normalize_fused_kernel<<<NRAYS / 256, 256, 0, stream>>>(out, bmin, bmax);
}